// Round 1
// baseline (354.351 us; speedup 1.0000x reference)
//
#include <hip/hip_runtime.h>

#define N_ITEMS 100000
#define HID 128
#define NNZ_T 1600000
#define EPB 512

// --- tiny transpose: WT[d][h] = W[h][d] ---
__global__ void transpose_w(const float* __restrict__ W, float* __restrict__ WT) {
    int idx = blockIdx.x * blockDim.x + threadIdx.x;   // 0..16383
    int r = idx >> 7, c = idx & 127;
    WT[c * HID + r] = W[r * HID + c];
}

// --- support = X @ W^T + b ---
// block tile: 32 rows x 128 cols, 256 threads, 4x4 per-thread tile, k-panels of 32
__global__ __launch_bounds__(256) void gemm_support(
    const float* __restrict__ X, const float* __restrict__ WT,
    const float* __restrict__ bias, float* __restrict__ S) {
    const int tid = threadIdx.x;
    const int tx = tid & 31;   // col group: cols 4*tx .. 4*tx+3
    const int ty = tid >> 5;   // row group: rows 4*ty .. 4*ty+3
    const int row0 = blockIdx.x * 32;

    __shared__ float xT[32][36];    // [k][row], stride 36 keeps float4 16B-aligned
    __shared__ float wt[32][128];   // [k][col]

    float acc[4][4] = {};

    for (int kp = 0; kp < HID; kp += 32) {
        // stage X tile transposed: rows row0..row0+31, k = kp..kp+31
#pragma unroll
        for (int i = 0; i < 4; ++i) {
            int r = ty + i * 8;           // 0..31
            xT[tx][r] = X[(size_t)(row0 + r) * HID + kp + tx];
        }
        // stage WT panel: 32 k-rows x 128 cols
#pragma unroll
        for (int i = 0; i < 16; ++i) {
            int idx = tid + i * 256;
            int kk = idx >> 7, c = idx & 127;
            wt[kk][c] = WT[(size_t)(kp + kk) * HID + c];
        }
        __syncthreads();
#pragma unroll
        for (int k = 0; k < 32; ++k) {
            float4 a = *(const float4*)&xT[k][ty * 4];
            float4 b = *(const float4*)&wt[k][tx * 4];
            acc[0][0] = fmaf(a.x, b.x, acc[0][0]);
            acc[0][1] = fmaf(a.x, b.y, acc[0][1]);
            acc[0][2] = fmaf(a.x, b.z, acc[0][2]);
            acc[0][3] = fmaf(a.x, b.w, acc[0][3]);
            acc[1][0] = fmaf(a.y, b.x, acc[1][0]);
            acc[1][1] = fmaf(a.y, b.y, acc[1][1]);
            acc[1][2] = fmaf(a.y, b.z, acc[1][2]);
            acc[1][3] = fmaf(a.y, b.w, acc[1][3]);
            acc[2][0] = fmaf(a.z, b.x, acc[2][0]);
            acc[2][1] = fmaf(a.z, b.y, acc[2][1]);
            acc[2][2] = fmaf(a.z, b.z, acc[2][2]);
            acc[2][3] = fmaf(a.z, b.w, acc[2][3]);
            acc[3][0] = fmaf(a.w, b.x, acc[3][0]);
            acc[3][1] = fmaf(a.w, b.y, acc[3][1]);
            acc[3][2] = fmaf(a.w, b.z, acc[3][2]);
            acc[3][3] = fmaf(a.w, b.w, acc[3][3]);
        }
        __syncthreads();
    }

    float4 bv = *(const float4*)&bias[tx * 4];
#pragma unroll
    for (int i = 0; i < 4; ++i) {
        int row = row0 + ty * 4 + i;
        float4 o;
        o.x = acc[i][0] + bv.x;
        o.y = acc[i][1] + bv.y;
        o.z = acc[i][2] + bv.z;
        o.w = acc[i][3] + bv.w;
        *(float4*)&S[(size_t)row * HID + tx * 4] = o;
    }
}

// --- out = A_coo @ S, rows sorted: run-accumulate, atomic only at block-boundary runs ---
__global__ __launch_bounds__(128) void spmm(
    const int* __restrict__ rows, const int* __restrict__ cols,
    const float* __restrict__ vals, const float* __restrict__ S,
    float* __restrict__ out) {
    __shared__ int   s_row[EPB];
    __shared__ int   s_col[EPB];
    __shared__ float s_val[EPB];

    const int tid = threadIdx.x;
    const int e0 = blockIdx.x * EPB;
    for (int i = tid; i < EPB; i += 128) {
        s_row[i] = rows[e0 + i];
        s_col[i] = cols[e0 + i];
        s_val[i] = vals[e0 + i];
    }
    __syncthreads();

    const int h = tid;             // one thread per hidden column
    float acc = 0.f;
    int cur = s_row[0];
    bool first = true;             // first run may extend into previous block

    for (int e = 0; e < EPB; ++e) {
        int r = s_row[e];
        if (r != cur) {            // uniform across the block — no divergence
            float* p = &out[(size_t)cur * HID + h];
            if (first) atomicAdd(p, acc);
            else       *p = acc;   // interior run: provably exclusive to this block
            first = false;
            acc = 0.f;
            cur = r;
        }
        acc = fmaf(s_val[e], S[(size_t)s_col[e] * HID + h], acc);
    }
    // last run may extend into the next block
    atomicAdd(&out[(size_t)cur * HID + h], acc);
}

extern "C" void kernel_launch(void* const* d_in, const int* in_sizes, int n_in,
                              void* d_out, int out_size, void* d_ws, size_t ws_size,
                              hipStream_t stream) {
    const float* X    = (const float*)d_in[0];
    const int*   rows = (const int*)  d_in[1];
    const int*   cols = (const int*)  d_in[2];
    const float* vals = (const float*)d_in[3];
    const float* W    = (const float*)d_in[4];
    const float* bias = (const float*)d_in[5];
    float* out = (float*)d_out;

    float* WT = (float*)d_ws;
    float* S  = WT + HID * HID;

    hipMemsetAsync(d_out, 0, (size_t)out_size * sizeof(float), stream);
    transpose_w<<<(HID * HID) / 256, 256, 0, stream>>>(W, WT);
    gemm_support<<<N_ITEMS / 32, 256, 0, stream>>>(X, WT, bias, S);
    spmm<<<NNZ_T / EPB, 128, 0, stream>>>(rows, cols, vals, S, out);
}

// Round 2
// 239.671 us; speedup vs baseline: 1.4785x; 1.4785x over previous
//
#include <hip/hip_runtime.h>

#define N_ITEMS 100000
#define HID 128
#define NNZ_T 1600000
#define EPB 256        // edges per spmm block (smaller -> more blocks -> full occupancy)
#define PF 8           // prefetch depth (independent gather loads in flight)

typedef unsigned short ushort_t;
typedef unsigned int uint_t;

static __device__ __forceinline__ ushort_t f32_to_bf16(float f) {
    uint_t u = __float_as_uint(f);
    uint_t r = (u + 0x7FFFu + ((u >> 16) & 1u)) >> 16;   // round-to-nearest-even
    return (ushort_t)r;
}
static __device__ __forceinline__ float bf16_to_f32(ushort_t h) {
    return __uint_as_float(((uint_t)h) << 16);
}

// --- tiny transpose: WT[d][h] = W[h][d] ---
__global__ void transpose_w(const float* __restrict__ W, float* __restrict__ WT) {
    int idx = blockIdx.x * blockDim.x + threadIdx.x;   // 0..16383
    int r = idx >> 7, c = idx & 127;
    WT[c * HID + r] = W[r * HID + c];
}

// --- support = X @ W^T + b, stored as bf16 ---
// block tile: 32 rows x 128 cols, 256 threads, 4x4 per-thread tile, k-panels of 32
__global__ __launch_bounds__(256) void gemm_support(
    const float* __restrict__ X, const float* __restrict__ WT,
    const float* __restrict__ bias, ushort_t* __restrict__ S) {
    const int tid = threadIdx.x;
    const int tx = tid & 31;   // col group: cols 4*tx .. 4*tx+3
    const int ty = tid >> 5;   // row group: rows 4*ty .. 4*ty+3
    const int row0 = blockIdx.x * 32;

    __shared__ float xT[32][36];    // [k][row], stride 36 keeps float4 16B-aligned
    __shared__ float wt[32][128];   // [k][col]

    float acc[4][4] = {};

    for (int kp = 0; kp < HID; kp += 32) {
#pragma unroll
        for (int i = 0; i < 4; ++i) {
            int r = ty + i * 8;
            xT[tx][r] = X[(size_t)(row0 + r) * HID + kp + tx];
        }
#pragma unroll
        for (int i = 0; i < 16; ++i) {
            int idx = tid + i * 256;
            int kk = idx >> 7, c = idx & 127;
            wt[kk][c] = WT[(size_t)(kp + kk) * HID + c];
        }
        __syncthreads();
#pragma unroll
        for (int k = 0; k < 32; ++k) {
            float4 a = *(const float4*)&xT[k][ty * 4];
            float4 b = *(const float4*)&wt[k][tx * 4];
            acc[0][0] = fmaf(a.x, b.x, acc[0][0]);
            acc[0][1] = fmaf(a.x, b.y, acc[0][1]);
            acc[0][2] = fmaf(a.x, b.z, acc[0][2]);
            acc[0][3] = fmaf(a.x, b.w, acc[0][3]);
            acc[1][0] = fmaf(a.y, b.x, acc[1][0]);
            acc[1][1] = fmaf(a.y, b.y, acc[1][1]);
            acc[1][2] = fmaf(a.y, b.z, acc[1][2]);
            acc[1][3] = fmaf(a.y, b.w, acc[1][3]);
            acc[2][0] = fmaf(a.z, b.x, acc[2][0]);
            acc[2][1] = fmaf(a.z, b.y, acc[2][1]);
            acc[2][2] = fmaf(a.z, b.z, acc[2][2]);
            acc[2][3] = fmaf(a.z, b.w, acc[2][3]);
            acc[3][0] = fmaf(a.w, b.x, acc[3][0]);
            acc[3][1] = fmaf(a.w, b.y, acc[3][1]);
            acc[3][2] = fmaf(a.w, b.z, acc[3][2]);
            acc[3][3] = fmaf(a.w, b.w, acc[3][3]);
        }
        __syncthreads();
    }

    float4 bv = *(const float4*)&bias[tx * 4];
#pragma unroll
    for (int i = 0; i < 4; ++i) {
        int row = row0 + ty * 4 + i;
        // pack 4 bf16 into 2 uints -> single 8B store
        ushort_t h0 = f32_to_bf16(acc[i][0] + bv.x);
        ushort_t h1 = f32_to_bf16(acc[i][1] + bv.y);
        ushort_t h2 = f32_to_bf16(acc[i][2] + bv.z);
        ushort_t h3 = f32_to_bf16(acc[i][3] + bv.w);
        uint2 packed;
        packed.x = (uint_t)h0 | ((uint_t)h1 << 16);
        packed.y = (uint_t)h2 | ((uint_t)h3 << 16);
        *(uint2*)&S[(size_t)row * HID + tx * 4] = packed;
    }
}

// --- out = A_coo @ S, rows sorted: run-accumulate, atomic only at block-boundary runs ---
// bf16 gather + 8-deep explicit prefetch to keep 8 loads in flight per thread.
__global__ __launch_bounds__(128) void spmm(
    const int* __restrict__ rows, const int* __restrict__ cols,
    const float* __restrict__ vals, const ushort_t* __restrict__ S,
    float* __restrict__ out) {
    __shared__ int   s_row[EPB];
    __shared__ int   s_col[EPB];
    __shared__ float s_val[EPB];

    const int tid = threadIdx.x;
    const int e0 = blockIdx.x * EPB;
    for (int i = tid; i < EPB; i += 128) {
        s_row[i] = rows[e0 + i];
        s_col[i] = cols[e0 + i];
        s_val[i] = vals[e0 + i];
    }
    __syncthreads();

    const int h = tid;             // one thread per hidden column
    float acc = 0.f;
    int cur = s_row[0];
    bool first = true;             // first run may extend into previous block

    for (int base = 0; base < EPB; base += PF) {
        float v[PF];
#pragma unroll
        for (int i = 0; i < PF; ++i) {
            // independent gather loads issued back-to-back (latency overlap)
            v[i] = bf16_to_f32(S[(size_t)s_col[base + i] * HID + h]);
        }
#pragma unroll
        for (int i = 0; i < PF; ++i) {
            int e = base + i;
            int r = s_row[e];
            if (r != cur) {        // uniform across the block
                float* p = &out[(size_t)cur * HID + h];
                if (first) atomicAdd(p, acc);
                else       *p = acc;   // interior run: exclusive to this block
                first = false;
                acc = 0.f;
                cur = r;
            }
            acc = fmaf(s_val[e], v[i], acc);
        }
    }
    atomicAdd(&out[(size_t)cur * HID + h], acc);   // last run may continue next block
}

extern "C" void kernel_launch(void* const* d_in, const int* in_sizes, int n_in,
                              void* d_out, int out_size, void* d_ws, size_t ws_size,
                              hipStream_t stream) {
    const float* X    = (const float*)d_in[0];
    const int*   rows = (const int*)  d_in[1];
    const int*   cols = (const int*)  d_in[2];
    const float* vals = (const float*)d_in[3];
    const float* W    = (const float*)d_in[4];
    const float* bias = (const float*)d_in[5];
    float* out = (float*)d_out;

    float*    WT = (float*)d_ws;
    ushort_t* S  = (ushort_t*)(WT + HID * HID);    // 100000*128*2B = 25.6 MB

    hipMemsetAsync(d_out, 0, (size_t)out_size * sizeof(float), stream);
    transpose_w<<<(HID * HID) / 256, 256, 0, stream>>>(W, WT);
    gemm_support<<<N_ITEMS / 32, 256, 0, stream>>>(X, WT, bias, S);
    spmm<<<NNZ_T / EPB, 128, 0, stream>>>(rows, cols, vals, S, out);
}

// Round 3
// 219.026 us; speedup vs baseline: 1.6178x; 1.0943x over previous
//
#include <hip/hip_runtime.h>

#define N_ITEMS 100000
#define HID 128
#define NNZ_T 1600000
#define EPW 128        // edges per wave in spmm
#define WPB 4          // waves per spmm block
#define PF 8           // gather prefetch depth

typedef unsigned short ushort_t;
typedef unsigned int uint_t;
typedef short bf16x8 __attribute__((ext_vector_type(8)));
typedef float f32x4 __attribute__((ext_vector_type(4)));

static __device__ __forceinline__ ushort_t f32_to_bf16(float f) {
    uint_t u = __float_as_uint(f);
    uint_t r = (u + 0x7FFFu + ((u >> 16) & 1u)) >> 16;   // RNE
    return (ushort_t)r;
}

// --- prep: W fp32 [128][128] row-major -> bf16 same layout (B operand of X*W^T) ---
__global__ void prep_w(const float* __restrict__ W, ushort_t* __restrict__ Wb) {
    int i = blockIdx.x * blockDim.x + threadIdx.x;   // 0..16383
    Wb[i] = f32_to_bf16(W[i]);
}

// --- support = X @ W^T + b via MFMA 16x16x32 bf16, stored bf16 ---
// block = 256 thr = 4 waves; wave computes 16-row x 128-col strip; K=128 in 4 steps.
// A frag: lane holds X[row0+(l&15)][kb*32+(l>>4)*8 ..+7] (contig 32B fp32 -> cvt bf16)
// B frag: lane holds W[nt*16+(l&15)][kb*32+(l>>4)*8 ..+7] (contig 16B bf16)
// C/D: col=lane&15, row=(lane>>4)*4+reg
__global__ __launch_bounds__(256) void gemm_mfma(
    const float* __restrict__ X, const ushort_t* __restrict__ Wb,
    const float* __restrict__ bias, ushort_t* __restrict__ S) {
    const int lane = threadIdx.x & 63;
    const int wave = threadIdx.x >> 6;
    const int m = lane & 15;
    const int q = lane >> 4;
    const int row0 = blockIdx.x * 64 + wave * 16;

    int arow = row0 + m;
    if (arow >= N_ITEMS) arow = N_ITEMS - 1;          // clamp (stores guarded)

    f32x4 acc[8] = {};

#pragma unroll
    for (int kb = 0; kb < 4; ++kb) {
        const int k0 = kb * 32 + q * 8;
        float4 a0 = *(const float4*)&X[(size_t)arow * HID + k0];
        float4 a1 = *(const float4*)&X[(size_t)arow * HID + k0 + 4];
        bf16x8 af;
        af[0] = (short)f32_to_bf16(a0.x); af[1] = (short)f32_to_bf16(a0.y);
        af[2] = (short)f32_to_bf16(a0.z); af[3] = (short)f32_to_bf16(a0.w);
        af[4] = (short)f32_to_bf16(a1.x); af[5] = (short)f32_to_bf16(a1.y);
        af[6] = (short)f32_to_bf16(a1.z); af[7] = (short)f32_to_bf16(a1.w);
#pragma unroll
        for (int nt = 0; nt < 8; ++nt) {
            bf16x8 bfr = *(const bf16x8*)&Wb[(size_t)(nt * 16 + m) * HID + k0];
            acc[nt] = __builtin_amdgcn_mfma_f32_16x16x32_bf16(af, bfr, acc[nt], 0, 0, 0);
        }
    }

#pragma unroll
    for (int nt = 0; nt < 8; ++nt) {
        const int col = nt * 16 + m;
        const float bv = bias[col];
#pragma unroll
        for (int r = 0; r < 4; ++r) {
            const int row = row0 + q * 4 + r;
            if (row < N_ITEMS)
                S[(size_t)row * HID + col] = f32_to_bf16(acc[nt][r] + bv);
        }
    }
}

// --- out = A_coo @ S: one WAVE per 128-edge chunk, lane owns 2 columns ---
// gather = one coalesced 256B wave-load per edge; run-accumulate, atomics only
// at chunk-boundary runs (rows globally sorted => interior runs exclusive).
__global__ __launch_bounds__(WPB * 64) void spmm(
    const int* __restrict__ rows, const int* __restrict__ cols,
    const float* __restrict__ vals, const ushort_t* __restrict__ S,
    float* __restrict__ out) {
    __shared__ int   s_row[WPB * EPW];
    __shared__ uint2 s_cv[WPB * EPW];    // (col, val-bits) packed for ds_read_b64

    const int tid = threadIdx.x;
    const int e0 = blockIdx.x * (WPB * EPW);
    for (int i = tid; i < WPB * EPW; i += WPB * 64) {
        s_row[i] = rows[e0 + i];
        s_cv[i] = make_uint2((uint_t)cols[e0 + i], __float_as_uint(vals[e0 + i]));
    }
    __syncthreads();

    const int wave = tid >> 6;
    const int lane = tid & 63;
    const int base0 = wave * EPW;

    float2 acc = make_float2(0.f, 0.f);
    int cur = s_row[base0];
    bool first = true;                   // first run may extend into previous chunk

    for (int g = 0; g < EPW; g += PF) {
        uint_t u[PF];
#pragma unroll
        for (int i = 0; i < PF; ++i) {   // independent gathers back-to-back
            uint_t c = s_cv[base0 + g + i].x;
            u[i] = *(const uint_t*)&S[(size_t)c * HID + 2 * lane];
        }
#pragma unroll
        for (int i = 0; i < PF; ++i) {
            const int e = base0 + g + i;
            const int r = s_row[e];
            if (r != cur) {              // wave-uniform (LDS broadcast)
                float* p = &out[(size_t)cur * HID + 2 * lane];
                if (first) { atomicAdd(p, acc.x); atomicAdd(p + 1, acc.y); }
                else       { *(float2*)p = acc; }     // interior run: exclusive
                first = false;
                acc = make_float2(0.f, 0.f);
                cur = r;
            }
            const float v = __uint_as_float(s_cv[e].y);
            const float f0 = __uint_as_float(u[i] << 16);
            const float f1 = __uint_as_float(u[i] & 0xFFFF0000u);
            acc.x = fmaf(v, f0, acc.x);
            acc.y = fmaf(v, f1, acc.y);
        }
    }
    float* p = &out[(size_t)cur * HID + 2 * lane];    // last run may continue on
    atomicAdd(p, acc.x); atomicAdd(p + 1, acc.y);
}

extern "C" void kernel_launch(void* const* d_in, const int* in_sizes, int n_in,
                              void* d_out, int out_size, void* d_ws, size_t ws_size,
                              hipStream_t stream) {
    const float* X    = (const float*)d_in[0];
    const int*   rows = (const int*)  d_in[1];
    const int*   cols = (const int*)  d_in[2];
    const float* vals = (const float*)d_in[3];
    const float* W    = (const float*)d_in[4];
    const float* bias = (const float*)d_in[5];
    float* out = (float*)d_out;

    ushort_t* Wb = (ushort_t*)d_ws;                    // 32 KB
    ushort_t* S  = Wb + HID * HID;                     // 25.6 MB bf16

    hipMemsetAsync(d_out, 0, (size_t)out_size * sizeof(float), stream);
    prep_w<<<(HID * HID) / 256, 256, 0, stream>>>(W, Wb);
    gemm_mfma<<<(N_ITEMS + 63) / 64, 256, 0, stream>>>(X, Wb, bias, S);
    spmm<<<NNZ_T / (WPB * EPW), WPB * 64, 0, stream>>>(rows, cols, vals, S, out);
}